// Round 1
// 1297.418 us; speedup vs baseline: 1.0150x; 1.0150x over previous
//
#include <hip/hip_runtime.h>
#include <stdint.h>

#define D_IN   768
#define D_DICT 16384
#define NROWS  8192
#define TOPK   32
#define CAND_TARGET 40   // screening candidate count (bf16 noise << rank-40 margin)
#define CAND_MAX    80   // strict hits in [0,40), ties packed from slot 79 down

typedef __attribute__((ext_vector_type(4))) float  f32x4;
typedef __attribute__((ext_vector_type(8))) short  s16x8;
typedef __attribute__((ext_vector_type(4))) unsigned short u16x4;

static __device__ __forceinline__ unsigned short f2bf(float f) {
    unsigned int u = __float_as_uint(f);
    unsigned int r = (u + 0x7FFFu + ((u >> 16) & 1u)) >> 16;   // RNE
    return (unsigned short)r;
}
// order-preserving map: bf16 bits -> u16 (monotone in float order)
static __device__ __forceinline__ unsigned short bfmap(unsigned short u) {
    return (u & 0x8000u) ? (unsigned short)(~u) : (unsigned short)(u | 0x8000u);
}

static __device__ __forceinline__ void gload_lds16(const void* g, void* l) {
    __builtin_amdgcn_global_load_lds(
        (const __attribute__((address_space(1))) unsigned int*)g,
        (__attribute__((address_space(3))) unsigned int*)l, 16, 0, 0);
}

// ---------------- prep: fp32 -> bf16 cast (vectorized) ----------------
__global__ __launch_bounds__(256) void cast_bf16(const float4* __restrict__ in,
                                                 u16x4* __restrict__ out, int n4) {
    int idx = blockIdx.x * 256 + threadIdx.x;
    if (idx >= n4) return;
    float4 v = in[idx];
    u16x4 o;
    o.x = f2bf(v.x); o.y = f2bf(v.y); o.z = f2bf(v.z); o.w = f2bf(v.w);
    out[idx] = o;
}

// ---------------- prep: transpose W_dec [768][16384] -> [16384][768] ----------------
__global__ void transpose_wdec(const float* __restrict__ in, float* __restrict__ out) {
    __shared__ float t[32][33];
    int bx = blockIdx.x, by = blockIdx.y;
    int tx = threadIdx.x, ty = threadIdx.y;
#pragma unroll
    for (int i = 0; i < 4; ++i)
        t[ty + i * 8][tx] = in[(size_t)(by * 32 + ty + i * 8) * D_DICT + bx * 32 + tx];
    __syncthreads();
#pragma unroll
    for (int i = 0; i < 4; ++i)
        out[(size_t)(bx * 32 + ty + i * 8) * D_IN + by * 32 + tx] = t[tx][ty + i * 8];
}

// ---------------- encode GEMM (screening, bf16 MFMA) + zsp tile zero-fill ----------------
// LDS tiles XOR-swizzled: row r's logical chunk c (16B) lives at physical chunk c^(r&7).
// Each block also zeroes its 128x128 tile of z_sparse (fire-and-forget stores issued
// at kernel start, fully overlapped with the MFMA K-loop) so sel_dec never has to.
__global__ __launch_bounds__(256) void gemm_enc(const unsigned short* __restrict__ Xb,
                                                const unsigned short* __restrict__ Wb,
                                                const float* __restrict__ bEnc,
                                                unsigned short* __restrict__ zhat,
                                                float* __restrict__ zsp) {
    __shared__ unsigned short As[128 * 64];
    __shared__ unsigned short Bs[128 * 64];
    const int tid    = threadIdx.x;
    const int waveId = tid >> 6;
    const int lane   = tid & 63;
    const int rowBase = blockIdx.y * 128;
    const int colBase = blockIdx.x * 128;
    const int wm = waveId >> 1, wn = waveId & 1;

    // zero this block's zsp tile: 128 rows x 128 cols = 64 KB, 16 float4/thread
    {
        float4 z4 = make_float4(0.f, 0.f, 0.f, 0.f);
        float4* zd = (float4*)(zsp + (size_t)rowBase * D_DICT + colBase);
#pragma unroll
        for (int i = 0; i < 16; ++i) {
            int slot = i * 256 + tid;          // 0..4095
            int rr = slot >> 5;                // row 0..127
            int cc = slot & 31;                // float4 col 0..31
            zd[(size_t)rr * (D_DICT / 4) + cc] = z4;
        }
    }

    f32x4 acc[4][4] = {};

    const int m0 = wm * 64 + (lane & 15);
    const int n0 = wn * 64 + (lane & 15);
    const int quad = lane >> 4;          // 0..3
    const int xa = m0 & 7;               // read-side XOR factor
    const int xb = n0 & 7;

    for (int k0 = 0; k0 < D_IN; k0 += 64) {
#pragma unroll
        for (int i = 0; i < 4; ++i) {
            int slot = i * 256 + tid;
            int r = slot >> 3;
            int cc = ((slot & 7) ^ (r & 7)) * 8;     // swizzled source chunk
            const unsigned short* ga = Xb + (size_t)(rowBase + r) * D_IN + k0 + cc;
            const unsigned short* gb = Wb + (size_t)(colBase + r) * D_IN + k0 + cc;
            unsigned short* la = As + (size_t)(i * 256 + waveId * 64) * 8;
            unsigned short* lb = Bs + (size_t)(i * 256 + waveId * 64) * 8;
            gload_lds16(ga, la);
            gload_lds16(gb, lb);
        }
        __syncthreads();
#pragma unroll
        for (int kk = 0; kk < 2; ++kk) {             // two 32-wide k-steps
            const int ch = kk * 4 + quad;            // logical chunk 0..7
            s16x8 a[4], b[4];
#pragma unroll
            for (int t = 0; t < 4; ++t) {
                a[t] = *(const s16x8*)(As + (m0 + t * 16) * 64 + ((ch ^ xa) << 3));
                b[t] = *(const s16x8*)(Bs + (n0 + t * 16) * 64 + ((ch ^ xb) << 3));
            }
#pragma unroll
            for (int mi = 0; mi < 4; ++mi)
#pragma unroll
                for (int ni = 0; ni < 4; ++ni)
                    acc[mi][ni] = __builtin_amdgcn_mfma_f32_16x16x32_bf16(
                        a[mi], b[ni], acc[mi][ni], 0, 0, 0);
        }
        __syncthreads();
    }

    const int col0 = colBase + wn * 64 + (lane & 15);
    const int rq   = (lane >> 4) * 4;
#pragma unroll
    for (int ni = 0; ni < 4; ++ni) {
        int gc = col0 + ni * 16;
        float bias = bEnc[gc];
#pragma unroll
        for (int mi = 0; mi < 4; ++mi) {
            int gr0 = rowBase + wm * 64 + mi * 16 + rq;
#pragma unroll
            for (int rg = 0; rg < 4; ++rg) {
                float v = acc[mi][ni][rg] + bias;
                zhat[(size_t)(gr0 + rg) * D_DICT + gc] = bfmap(f2bf(v));
            }
        }
    }
}

// ---------------- merged: select top-32 + scatter z + fused decode ----------------
// One row per block. zsp rows are pre-zeroed by gemm_enc; only the 32-element
// scatter and xhat remain as writes here.
__global__ __launch_bounds__(256) void sel_dec(const unsigned short* __restrict__ zhat,
                                               const float* __restrict__ x,
                                               const float* __restrict__ wEnc,
                                               const float* __restrict__ bEnc,
                                               const float* __restrict__ wDecT,
                                               const float* __restrict__ bDec,
                                               float* __restrict__ zsp,
                                               float* __restrict__ xhat) {
    const int row = blockIdx.x;
    const int tid = threadIdx.x;
    const int waveId = tid >> 6;

    __shared__ int   histc[4][256];    // per-wave histogram copies
    alignas(16) __shared__ float xs[D_IN];
    __shared__ int   cidx[CAND_MAX];
    __shared__ float zc[CAND_MAX];
    __shared__ int   selk[TOPK];
    __shared__ float selv[TOPK];
    __shared__ int   sh_bin, sh_cum, sh_bin2;
    __shared__ int   sh_nstrict, sh_ntie, sh_nsel;

    // load this row's 64 screened values into registers (issued first)
    uint4 r[8];
    const uint4* zr4 = (const uint4*)(zhat + (size_t)row * D_DICT);
#pragma unroll
    for (int i = 0; i < 8; ++i) r[i] = zr4[i * 256 + tid];

    // stage x row into LDS (vectorized)
    if (tid < 192)
        ((float4*)xs)[tid] = ((const float4*)(x + (size_t)row * D_IN))[tid];
    if (tid == 0) { sh_nstrict = 0; sh_ntie = 0; sh_nsel = 0; }

    // -------- two-level radix cut with static floor + fallback --------
    unsigned int floorU = 0xBF80u;  // mapped bf16(1.0); ~4% pass (rank-80 at z~1.5)
    int shift1 = 6;
    const int T = CAND_TARGET;

    for (int att = 0; att < 2; ++att) {
        for (int b = tid; b < 1024; b += 256) ((int*)histc)[b] = 0;
        if (tid == 0) sh_bin = -1;
        __syncthreads();
#pragma unroll
        for (int i = 0; i < 8; ++i) {
            unsigned int w[4] = {r[i].x, r[i].y, r[i].z, r[i].w};
#pragma unroll
            for (int q = 0; q < 4; ++q)
#pragma unroll
                for (int h = 0; h < 2; ++h) {
                    unsigned int u = (w[q] >> (16 * h)) & 0xFFFFu;
                    if (u >= floorU) {
                        int bin = (int)((u - floorU) >> shift1);
                        if (bin > 255) bin = 255;
                        atomicAdd(&histc[waveId][bin], 1);
                    }
                }
        }
        __syncthreads();
        if (tid < 256) histc[0][tid] += histc[1][tid] + histc[2][tid] + histc[3][tid];
        __syncthreads();
        if (tid < 64) {  // wave-0 descending prefix scan over 256 bins
            int l = tid;
            int b0 = 255 - l * 4;
            int s0 = histc[0][b0], s1 = histc[0][b0 - 1],
                s2 = histc[0][b0 - 2], s3 = histc[0][b0 - 3];
            int local = s0 + s1 + s2 + s3;
            int pref = local;
#pragma unroll
            for (int off = 1; off < 64; off <<= 1) {
                int n = __shfl_up(pref, off, 64);
                if (l >= off) pref += n;
            }
            unsigned long long m = __ballot(pref >= T);
            if (m) {
                int first = (int)__ffsll(m) - 1;
                if (l == first) {
                    int cum = pref - local;
                    int b, c;
                    if      (cum + s0 >= T)           { b = b0;     c = cum; }
                    else if (cum + s0 + s1 >= T)      { b = b0 - 1; c = cum + s0; }
                    else if (cum + s0 + s1 + s2 >= T) { b = b0 - 2; c = cum + s0 + s1; }
                    else                              { b = b0 - 3; c = cum + s0 + s1 + s2; }
                    sh_bin = b; sh_cum = c;
                }
            }
        }
        __syncthreads();
        if (sh_bin >= 0) break;
        floorU = 0u; shift1 = 8;   // fallback: full-range histogram (unreachable in practice)
    }
    const int b1 = sh_bin;
    const int cumAbove = sh_cum;
    const int s2 = shift1 - 6;     // 64 sub-bins

    // -------- fine pass within coarse bin b1 --------
    for (int b = tid; b < 1024; b += 256) ((int*)histc)[b] = 0;
    __syncthreads();
#pragma unroll
    for (int i = 0; i < 8; ++i) {
        unsigned int w[4] = {r[i].x, r[i].y, r[i].z, r[i].w};
#pragma unroll
        for (int q = 0; q < 4; ++q)
#pragma unroll
            for (int h = 0; h < 2; ++h) {
                unsigned int u = (w[q] >> (16 * h)) & 0xFFFFu;
                if (u >= floorU) {
                    int bin = (int)((u - floorU) >> shift1);
                    if (bin > 255) bin = 255;
                    if (bin == b1) {
                        int bin2 = (int)(((u - floorU) >> s2) & 63u);
                        atomicAdd(&histc[waveId][bin2], 1);
                    }
                }
            }
    }
    __syncthreads();
    if (tid < 64) {  // wave-0 descending scan over 64 sub-bins
        int l = tid;
        int bb = 63 - l;
        int local = histc[0][bb] + histc[1][bb] + histc[2][bb] + histc[3][bb];
        int pref = local;
#pragma unroll
        for (int off = 1; off < 64; off <<= 1) {
            int n = __shfl_up(pref, off, 64);
            if (l >= off) pref += n;
        }
        unsigned long long m = __ballot(cumAbove + pref >= T);
        int first = (int)__ffsll(m) - 1;
        if (l == first) sh_bin2 = bb;
    }
    __syncthreads();
    const unsigned int tieLo  = floorU + ((unsigned)b1 << shift1) + ((unsigned)sh_bin2 << s2);
    const unsigned int tieTop = tieLo + (1u << s2) - 1u;

    // -------- collect candidates from registers --------
#pragma unroll
    for (int i = 0; i < 8; ++i) {
        unsigned int w[4] = {r[i].x, r[i].y, r[i].z, r[i].w};
#pragma unroll
        for (int q = 0; q < 4; ++q)
#pragma unroll
            for (int h = 0; h < 2; ++h) {
                unsigned int u = (w[q] >> (16 * h)) & 0xFFFFu;
                if (u > tieTop) {
                    int p = atomicAdd(&sh_nstrict, 1);   // < CAND_TARGET guaranteed
                    cidx[p] = (i * 256 + tid) * 8 + q * 2 + h;
                } else if (u >= tieLo) {
                    int t = atomicAdd(&sh_ntie, 1);
                    if (t < CAND_TARGET) cidx[CAND_MAX - 1 - t] = (i * 256 + tid) * 8 + q * 2 + h;
                }
            }
    }
    __syncthreads();
    const int nstrict = sh_nstrict;
    const int nt = min(sh_ntie, CAND_TARGET);
    int tmpv = 0;
    if (tid < nt) tmpv = cidx[CAND_MAX - 1 - tid];
    __syncthreads();
    if (tid < nt) cidx[nstrict + tid] = tmpv;
    __syncthreads();
    const int nc = nstrict + nt;   // in [CAND_TARGET, CAND_MAX)

    // -------- fp64-exact refinement: 8 lanes per candidate, float4 coalesced --------
    // Lane sub of an 8-lane group reads float4 indices {sub, sub+8, ...}: at each
    // step the group covers one full 128B cacheline of the wEnc row. Four
    // independent fp64 accumulators break the dependency chain.
    const int sub = tid & 7;
    const int cq  = tid >> 3;               // 0..31 candidates per round
    for (int c0 = 0; c0 < nc; c0 += 32) {
        int c = c0 + cq;
        double a0 = 0.0, a1 = 0.0, a2 = 0.0, a3 = 0.0;
        int k = 0;
        if (c < nc) {
            k = cidx[c];
            const float4* wp = (const float4*)(wEnc + (size_t)k * D_IN);
            const float4* xp = (const float4*)xs;
#pragma unroll 8
            for (int j = 0; j < 24; ++j) {
                float4 wv = wp[j * 8 + sub];
                float4 xv = xp[j * 8 + sub];
                a0 += (double)xv.x * (double)wv.x;
                a1 += (double)xv.y * (double)wv.y;
                a2 += (double)xv.z * (double)wv.z;
                a3 += (double)xv.w * (double)wv.w;
            }
        }
        double acc = (a0 + a1) + (a2 + a3);
        acc += __shfl_xor(acc, 1, 64);
        acc += __shfl_xor(acc, 2, 64);
        acc += __shfl_xor(acc, 4, 64);
        if (c < nc && sub == 0) zc[c] = (float)(acc + (double)bEnc[k]);
    }
    __syncthreads();

    // -------- exact rank (fp32 values, lower-index tie-break) -> top-32 --------
    if (tid < nc) {
        float v = zc[tid];
        int   k = cidx[tid];
        int rk = 0;
        for (int j = 0; j < nc; ++j) {
            float vj = zc[j];
            if (vj > v || (vj == v && cidx[j] < k)) ++rk;
        }
        if (rk < TOPK) {
            int s = atomicAdd(&sh_nsel, 1);
            selk[s] = k; selv[s] = v;
        }
    }
    __syncthreads();

    if (tid < TOPK) zsp[(size_t)row * D_DICT + selk[tid]] = selv[tid];

    // fused decode: x_hat[row] = sum_j selv[j] * W_decT[selk[j], :] + b_dec
    // 192 threads x float4 covers all 768 outputs; 32 gathered float4 loads each.
    if (tid < 192) {
        float4 acc = ((const float4*)bDec)[tid];
#pragma unroll 8
        for (int j = 0; j < TOPK; ++j) {
            const float4* wr = (const float4*)(wDecT + (size_t)selk[j] * D_IN);
            float4 wv = wr[tid];
            float s = selv[j];
            acc.x += s * wv.x; acc.y += s * wv.y;
            acc.z += s * wv.z; acc.w += s * wv.w;
        }
        ((float4*)(xhat + (size_t)row * D_IN))[tid] = acc;
    }
}

extern "C" void kernel_launch(void* const* d_in, const int* in_sizes, int n_in,
                              void* d_out, int out_size, void* d_ws, size_t ws_size,
                              hipStream_t stream) {
    const float* x    = (const float*)d_in[0];
    const float* wEnc = (const float*)d_in[1];
    const float* bEnc = (const float*)d_in[2];
    const float* wDec = (const float*)d_in[3];
    const float* bDec = (const float*)d_in[4];

    float* xhat = (float*)d_out;                          // [8192][768]
    float* zsp  = (float*)d_out + (size_t)NROWS * D_IN;   // [8192][16384]

    char* ws = (char*)d_ws;
    unsigned short* Xb   = (unsigned short*)ws;                                 // 12.6 MB
    unsigned short* Wb   = (unsigned short*)(ws + (size_t)NROWS * D_IN * 2);    // 25.2 MB
    float*          WdT  = (float*)(ws + (size_t)NROWS * D_IN * 2
                                       + (size_t)D_DICT * D_IN * 2);            // 50.3 MB
    unsigned short* zhat = (unsigned short*)(ws + 88080384);                    // 268 MB (u16[8192][16384])

    {
        int n4 = NROWS * D_IN / 4;
        cast_bf16<<<(n4 + 255) / 256, 256, 0, stream>>>((const float4*)x, (u16x4*)Xb, n4);
    }
    {
        int n4 = D_DICT * D_IN / 4;
        cast_bf16<<<(n4 + 255) / 256, 256, 0, stream>>>((const float4*)wEnc, (u16x4*)Wb, n4);
    }
    transpose_wdec<<<dim3(D_DICT / 32, D_IN / 32), dim3(32, 8), 0, stream>>>(wDec, WdT);
    gemm_enc<<<dim3(D_DICT / 128, NROWS / 128), 256, 0, stream>>>(Xb, Wb, bEnc, zhat, zsp);
    sel_dec<<<NROWS, 256, 0, stream>>>(zhat, x, wEnc, bEnc, WdT, bDec, zsp, xhat);
}